// Round 2
// baseline (346.833 us; speedup 1.0000x reference)
//
#include <hip/hip_runtime.h>
#include <stdint.h>

// Problem constants
#define SEQ   2048
#define NNODE 16384      // B*S = 8*2048

typedef short  short8  __attribute__((ext_vector_type(8)));   // 8 bf16 (4 VGPR)
typedef float  float4v __attribute__((ext_vector_type(4)));
typedef unsigned short u16;
typedef unsigned short u16x8 __attribute__((ext_vector_type(8)));
typedef short  short4v __attribute__((ext_vector_type(4)));

__device__ __forceinline__ float b2f(u16 u) {
    union { unsigned int i; float f; } x; x.i = ((unsigned int)u) << 16; return x.f;
}
__device__ __forceinline__ u16 f2b(float f) {
    union { float f; unsigned int i; } x; x.f = f;
    unsigned int u = x.i;
    unsigned int r = (u + 0x7fffu + ((u >> 16) & 1u)) >> 16;  // RNE
    return (u16)r;
}

__device__ __forceinline__ void gld16(const void* g, void* l) {
    __builtin_amdgcn_global_load_lds(
        (const __attribute__((address_space(1))) void*)g,
        (__attribute__((address_space(3))) void*)l, 16, 0, 0);
}

// ---------------------------------------------------------------------------
// fp32 -> bf16 convert for h_x / h_y (16,777,216 elems per side)
// ---------------------------------------------------------------------------
__global__ __launch_bounds__(256) void cvt_k(const float* __restrict__ s0,
                                             const float* __restrict__ s1,
                                             u16* __restrict__ d) {
    const float* s = blockIdx.y ? s1 : s0;
    u16* dd = d + (size_t)blockIdx.y * 16777216u;
    const size_t i = ((size_t)blockIdx.x * 256 + threadIdx.x) * 8;
    float4v a = *(const float4v*)(s + i);
    float4v b = *(const float4v*)(s + i + 4);
    u16x8 r;
    r[0] = f2b(a[0]); r[1] = f2b(a[1]); r[2] = f2b(a[2]); r[3] = f2b(a[3]);
    r[4] = f2b(b[0]); r[5] = f2b(b[1]); r[6] = f2b(b[2]); r[7] = f2b(b[3]);
    *(u16x8*)(dd + i) = r;
}

// ---------------------------------------------------------------------------
// Generic 128x128 tile bf16 GEMM:  C[M,N] = act(A[M,K] @ B^T[N,K] + bias)
// blockIdx.z selects pointer set (batches both sides / msg+self in 1 launch).
// LDS 16B-chunk XOR swizzle: slot (row, c) holds global chunk (row, c^(row&7))
//  -> global_load_lds stays lane-contiguous in LDS, frag ds_read_b128 is
//     bank-conflict-free.
// ---------------------------------------------------------------------------
struct GemmP {
    const u16*   A[4];
    const u16*   B[4];
    const float* bias[4];
    u16*         out[4];
};

template <int ACT>
__global__ __launch_bounds__(256) void gemm_k(GemmP p, int M, int N, int K) {
    __shared__ __align__(16) u16 As[128 * 64];
    __shared__ __align__(16) u16 Bs[128 * 64];

    const int z = blockIdx.z;
    const u16*   __restrict__ A    = p.A[z];
    const u16*   __restrict__ B    = p.B[z];
    const float* __restrict__ bias = p.bias[z];

    const int mt  = blockIdx.x * 128;
    const int nt  = blockIdx.y * 128;
    const int tid = threadIdx.x;
    const int l   = tid & 63;
    const int w   = tid >> 6;
    const int wm  = (w >> 1) * 64;
    const int wn  = (w & 1) * 64;
    const int lr  = l & 15;   // MFMA row/col within 16
    const int lk  = l >> 4;   // MFMA k-chunk group (0..3)

    float4v acc[4][4] = {};

    for (int k0 = 0; k0 < K; k0 += 64) {
        // stage A & B tiles (128 rows x 64 k, bf16) via async direct-to-LDS
#pragma unroll
        for (int it = 0; it < 4; ++it) {
            int f  = it * 256 + tid;       // 16B chunk id, lane-contiguous
            int rm = f >> 3, cc = f & 7;
            int gc = cc ^ (rm & 7);        // permute source so swizzle lands
            gld16(A + (size_t)(mt + rm) * K + (k0 + gc * 8), As + (size_t)f * 8);
            gld16(B + (size_t)(nt + rm) * K + (k0 + gc * 8), Bs + (size_t)f * 8);
        }
        __syncthreads();
#pragma unroll
        for (int ks = 0; ks < 2; ++ks) {
            short8 af[4], bfr[4];
            const int kc = ks * 4 + lk;
#pragma unroll
            for (int i = 0; i < 4; ++i) {
                int ra = wm + i * 16 + lr;
                af[i]  = *(const short8*)(As + ((size_t)ra * 8 + (kc ^ (ra & 7))) * 8);
                int rb = wn + i * 16 + lr;
                bfr[i] = *(const short8*)(Bs + ((size_t)rb * 8 + (kc ^ (rb & 7))) * 8);
            }
#pragma unroll
            for (int i = 0; i < 4; ++i)
#pragma unroll
                for (int j = 0; j < 4; ++j)
                    acc[i][j] = __builtin_amdgcn_mfma_f32_16x16x32_bf16(
                        af[i], bfr[j], acc[i][j], 0, 0, 0);
        }
        __syncthreads();
    }

    // epilogue: C/D layout col=lane&15, row=(lane>>4)*4+reg  [verified m89/m91]
    const int r0 = lk * 4;
#pragma unroll
    for (int j = 0; j < 4; ++j) {
        const int gn = nt + wn + j * 16 + lr;
        const float bv = bias[gn];
#pragma unroll
        for (int i = 0; i < 4; ++i) {
            const int gm = mt + wm + i * 16 + r0;
#pragma unroll
            for (int r = 0; r < 4; ++r) {
                float v = acc[i][j][r] + bv;
                if (ACT) v = v > 0.f ? v : 0.01f * v;   // jax leaky_relu slope
                p.out[z][(size_t)(gm + r) * N + gn] = f2b(v);
            }
        }
    }
}

// ---------------------------------------------------------------------------
// Weight transpose (fp32 [K,N] -> bf16 [N,K]) for the 6 GEMM B-operands
// ---------------------------------------------------------------------------
struct TP { const float* src[6]; u16* dst[6]; int K[6]; int N[6]; };

__global__ void transpose_k(TP t) {
    const int m  = blockIdx.y;
    const int KN = t.K[m] * t.N[m];
    const int flat = blockIdx.x * 256 + threadIdx.x;
    if (flat >= KN) return;
    const int n = flat % t.N[m];
    const int k = flat / t.N[m];
    t.dst[m][(size_t)n * t.K[m] + k] = f2b(t.src[m][flat]);
}

// EW[t][c] = sum_e emb[t][e] * W_edge[e][c]   (64x256, fp32)
__global__ void ew_k(const float* emb, const float* W_edge, float* EW) {
    const int t = blockIdx.x, c = threadIdx.x;
    float s = 0.f;
    for (int e = 0; e < 64; ++e)
        s += emb[t * 64 + e] * W_edge[e * 256 + c];
    EW[t * 256 + c] = s;
}

// ---------------------------------------------------------------------------
// Epilogue: out_i = xself[i] + valid_i*(xmsg[head_i] + EW[type_i]);
//           L2-normalize; accumulate per-batch sum (later /2048).
// alpha == valid exactly (dst=arange -> singleton segments -> softmax = 1).
// Block = 4 waves; wave handles 8 nodes; lane owns channels [4l, 4l+4).
// ---------------------------------------------------------------------------
struct EpiP {
    const u16* xmsg[2]; const u16* xself[2];
    const int* den[2]; const int* spa[2]; const int* arc[2];
    const int* wty[2]; const int* wma[2];
    const float* EW; float* racc;
};

__global__ __launch_bounds__(256) void epi_k(EpiP p) {
    __shared__ float part[4][256];
    const int bx    = blockIdx.x;
    const int side  = bx >> 9;           // 512 blocks per side
    const int local = bx & 511;
    const int base  = local * 32;        // 32 nodes/block (same batch: 32|2048)
    const int b     = base >> 11;
    const int tid   = threadIdx.x;
    const int w = tid >> 6, l = tid & 63;

    const u16* __restrict__ xmsg  = p.xmsg[side];
    const u16* __restrict__ xself = p.xself[side];

    float4v acc = {};
    for (int j = 0; j < 8; ++j) {
        const int i     = base + w * 8 + j;
        const int valid = p.den[side][i] * p.spa[side][i];
        const int srcn  = p.arc[side][i] + (i >> 11) * SEQ;
        const int t     = p.wty[side][i] * p.wma[side][i];
        short4v xs = *(const short4v*)(xself + (size_t)i * 256 + l * 4);
        short4v xm = *(const short4v*)(xmsg + (size_t)srcn * 256 + l * 4);
        float4v ew = *(const float4v*)(p.EW + (size_t)t * 256 + l * 4);
        const float vm = valid ? 1.f : 0.f;
        float4v v;
        v[0] = b2f((u16)xs[0]) + vm * (b2f((u16)xm[0]) + ew[0]);
        v[1] = b2f((u16)xs[1]) + vm * (b2f((u16)xm[1]) + ew[1]);
        v[2] = b2f((u16)xs[2]) + vm * (b2f((u16)xm[2]) + ew[2]);
        v[3] = b2f((u16)xs[3]) + vm * (b2f((u16)xm[3]) + ew[3]);
        float ss = v[0]*v[0] + v[1]*v[1] + v[2]*v[2] + v[3]*v[3];
        for (int m = 32; m >= 1; m >>= 1) ss += __shfl_xor(ss, m, 64);
        const float rn = 1.f / fmaxf(sqrtf(ss), 1e-12f);
        acc[0] += v[0] * rn; acc[1] += v[1] * rn;
        acc[2] += v[2] * rn; acc[3] += v[3] * rn;
    }
    part[w][l * 4 + 0] = acc[0];
    part[w][l * 4 + 1] = acc[1];
    part[w][l * 4 + 2] = acc[2];
    part[w][l * 4 + 3] = acc[3];
    __syncthreads();
    const float s = part[0][tid] + part[1][tid] + part[2][tid] + part[3][tid];
    atomicAdd(p.racc + ((size_t)side * 8 + b) * 256 + tid, s);
}

// out[side,b,c] = (racc[side,b,:]/2048) @ Wf[:,c] + bf[c]   (fp32 out)
__global__ void fin_k(const float* racc, const float* Wf, const float* bfv,
                      float* out) {
    __shared__ float r[256];
    const int bid = blockIdx.x;   // side*8 + b, 0..15
    const int tid = threadIdx.x;
    r[tid] = racc[bid * 256 + tid] * (1.f / 2048.f);
    __syncthreads();
    float s = bfv[tid];
    for (int k = 0; k < 256; ++k)
        s += r[k] * Wf[k * 256 + tid];
    out[bid * 256 + tid] = s;
}

// ---------------------------------------------------------------------------
extern "C" void kernel_launch(void* const* d_in, const int* in_sizes, int n_in,
                              void* d_out, int out_size, void* d_ws, size_t ws_size,
                              hipStream_t stream) {
    // setup_inputs() dict order; float tensors are fp32, index tensors int32
    const float* h[2]   = {(const float*)d_in[0],  (const float*)d_in[1]};
    const int* den[2]   = {(const int*)d_in[4],  (const int*)d_in[11]};
    const int* spa[2]   = {(const int*)d_in[5],  (const int*)d_in[12]};
    const int* arc[2]   = {(const int*)d_in[7],  (const int*)d_in[14]};
    const int* wty[2]   = {(const int*)d_in[9],  (const int*)d_in[16]};
    const int* wma[2]   = {(const int*)d_in[10], (const int*)d_in[17]};
    const float* W1[2]  = {(const float*)d_in[18], (const float*)d_in[22]};
    const float* b1[2]  = {(const float*)d_in[19], (const float*)d_in[23]};
    const float* W2[2]  = {(const float*)d_in[20], (const float*)d_in[24]};
    const float* b2[2]  = {(const float*)d_in[21], (const float*)d_in[25]};
    const float* emb    = (const float*)d_in[26];
    const float* Wmsg   = (const float*)d_in[27];
    const float* bmsg   = (const float*)d_in[28];
    const float* Wedge  = (const float*)d_in[29];
    const float* Wself  = (const float*)d_in[31];
    const float* bself  = (const float*)d_in[32];
    const float* Wf     = (const float*)d_in[33];
    const float* bf_    = (const float*)d_in[34];

    char* ws = (char*)d_ws;
    size_t off = 0;
    auto alloc = [&](size_t bytes) -> void* {
        void* pp = ws + off; off += (bytes + 255) & ~(size_t)255; return pp;
    };
    // hbf dead after GEMM1/2 consume it -> xmsg/xself alias its region
    u16*   hbf   = (u16*)  alloc(2ull * NNODE * 1024 * 2);  // 64 MB, bf16 h
    u16*   x1    = (u16*)  alloc(2ull * NNODE * 512 * 2);   // 32 MB
    u16*   xx    = (u16*)  alloc(2ull * NNODE * 256 * 2);   // 16 MB
    u16*   W1T   = (u16*)  alloc(2ull * 512 * 1024 * 2);
    u16*   W2T   = (u16*)  alloc(2ull * 256 * 512 * 2);
    u16*   WmsgT = (u16*)  alloc(256 * 256 * 2);
    u16*   WselfT= (u16*)  alloc(256 * 256 * 2);
    float* EW    = (float*)alloc(64 * 256 * 4);
    float* racc  = (float*)alloc(2 * 8 * 256 * 4);
    u16*   xmsg  = hbf;                                     // alias (GEMM3 runs after GEMM1)
    u16*   xself = hbf + 2ull * NNODE * 256;

    // prep: h fp32->bf16; weights transpose+convert to [N,K] bf16
    hipLaunchKernelGGL(cvt_k, dim3(8192, 2), dim3(256), 0, stream,
                       h[0], h[1], hbf);
    TP tp;
    tp.src[0] = W1[0]; tp.dst[0] = W1T;              tp.K[0] = 1024; tp.N[0] = 512;
    tp.src[1] = W1[1]; tp.dst[1] = W1T + 512 * 1024; tp.K[1] = 1024; tp.N[1] = 512;
    tp.src[2] = W2[0]; tp.dst[2] = W2T;              tp.K[2] = 512;  tp.N[2] = 256;
    tp.src[3] = W2[1]; tp.dst[3] = W2T + 256 * 512;  tp.K[3] = 512;  tp.N[3] = 256;
    tp.src[4] = Wmsg;  tp.dst[4] = WmsgT;            tp.K[4] = 256;  tp.N[4] = 256;
    tp.src[5] = Wself; tp.dst[5] = WselfT;           tp.K[5] = 256;  tp.N[5] = 256;
    hipLaunchKernelGGL(transpose_k, dim3(2048, 6), dim3(256), 0, stream, tp);
    hipLaunchKernelGGL(ew_k, dim3(64), dim3(256), 0, stream, emb, Wedge, EW);
    hipMemsetAsync(racc, 0, 2 * 8 * 256 * 4, stream);

    // GEMM1: [16384,1024]@[1024,512] + b1, leaky_relu -> x1 (bf16), both sides
    GemmP g1 = {};
    g1.A[0] = hbf;   g1.A[1] = hbf + 2ull * NNODE * 512;
    g1.B[0] = W1T;   g1.B[1] = W1T + 512 * 1024;
    g1.bias[0] = b1[0]; g1.bias[1] = b1[1];
    g1.out[0] = x1;  g1.out[1] = x1 + (size_t)NNODE * 512;
    hipLaunchKernelGGL((gemm_k<1>), dim3(128, 4, 2), dim3(256), 0, stream,
                       g1, NNODE, 512, 1024);

    // GEMM2: [16384,512]@[512,256] + b2 -> x (bf16), both sides
    GemmP g2 = {};
    g2.A[0] = x1;  g2.A[1] = x1 + (size_t)NNODE * 512;
    g2.B[0] = W2T; g2.B[1] = W2T + 256 * 512;
    g2.bias[0] = b2[0]; g2.bias[1] = b2[1];
    g2.out[0] = xx; g2.out[1] = xx + (size_t)NNODE * 256;
    hipLaunchKernelGGL((gemm_k<0>), dim3(128, 2, 2), dim3(256), 0, stream,
                       g2, NNODE, 256, 512);

    // GEMM3/4: x@W_msg + b_msg -> xmsg, x@W_self + b_self -> xself, both sides
    GemmP g3 = {};
    g3.A[0] = xx; g3.A[1] = xx;
    g3.A[2] = xx + (size_t)NNODE * 256; g3.A[3] = xx + (size_t)NNODE * 256;
    g3.B[0] = WmsgT; g3.B[1] = WselfT; g3.B[2] = WmsgT; g3.B[3] = WselfT;
    g3.bias[0] = bmsg; g3.bias[1] = bself; g3.bias[2] = bmsg; g3.bias[3] = bself;
    g3.out[0] = xmsg;  g3.out[1] = xself;
    g3.out[2] = xmsg + (size_t)NNODE * 256; g3.out[3] = xself + (size_t)NNODE * 256;
    hipLaunchKernelGGL((gemm_k<0>), dim3(128, 2, 4), dim3(256), 0, stream,
                       g3, NNODE, 256, 256);

    // gather + mask + L2-normalize + per-batch mean accumulation
    EpiP ep;
    ep.xmsg[0]  = xmsg;  ep.xmsg[1]  = xmsg + (size_t)NNODE * 256;
    ep.xself[0] = xself; ep.xself[1] = xself + (size_t)NNODE * 256;
    for (int s = 0; s < 2; ++s) {
        ep.den[s] = den[s]; ep.spa[s] = spa[s]; ep.arc[s] = arc[s];
        ep.wty[s] = wty[s]; ep.wma[s] = wma[s];
    }
    ep.EW = EW; ep.racc = racc;
    hipLaunchKernelGGL(epi_k, dim3(1024), dim3(256), 0, stream, ep);

    // final projection -> d_out (fp32, src then tgt, 2*8*256)
    hipLaunchKernelGGL(fin_k, dim3(16), dim3(256), 0, stream,
                       racc, Wf, bf_, (float*)d_out);
}

// Round 3
// 319.817 us; speedup vs baseline: 1.0845x; 1.0845x over previous
//
#include <hip/hip_runtime.h>
#include <stdint.h>

// Problem constants
#define SEQ   2048
#define NNODE 16384      // B*S = 8*2048

typedef short  short8  __attribute__((ext_vector_type(8)));   // 8 bf16 (4 VGPR)
typedef float  float4v __attribute__((ext_vector_type(4)));
typedef unsigned short u16;
typedef unsigned short u16x8 __attribute__((ext_vector_type(8)));
typedef short  short4v __attribute__((ext_vector_type(4)));

__device__ __forceinline__ float b2f(u16 u) {
    union { unsigned int i; float f; } x; x.i = ((unsigned int)u) << 16; return x.f;
}
__device__ __forceinline__ u16 f2b(float f) {
    union { float f; unsigned int i; } x; x.f = f;
    unsigned int u = x.i;
    unsigned int r = (u + 0x7fffu + ((u >> 16) & 1u)) >> 16;  // RNE
    return (u16)r;
}

__device__ __forceinline__ void gld16(const void* g, void* l) {
    __builtin_amdgcn_global_load_lds(
        (const __attribute__((address_space(1))) void*)g,
        (__attribute__((address_space(3))) void*)l, 16, 0, 0);
}

// ---------------------------------------------------------------------------
// Generic 128x128 tile bf16 GEMM:  C[M,N] = act(A[M,K] @ B^T[N,K] + bias)
// AF32=1: A is fp32 in global; staged with in-register bf16 convert +
//         ds_write_b128 (removes the separate cvt pass).
// AF32=0: A is bf16; staged via global_load_lds width=16.
// LDS 16B-chunk XOR swizzle: slot (row, c) holds global chunk (row, c^(row&7))
//  -> lane-contiguous staging, conflict-free ds_read_b128 fragments.
// Epilogue: acc -> LDS (u16, row stride 136) -> dwordx4 global stores
//  (write amplification 1.0 instead of 1.5 with scalar 2B stores).
// ---------------------------------------------------------------------------
struct GemmP {
    const void*  A[2];
    const u16*   B[2];
    const float* bias[2];
    u16*         out[2];
};

#define LDW 136   // epilogue LDS row stride in u16 (272B: 16B-aligned rows)

template <int ACT, int AF32>
__global__ __launch_bounds__(256) void gemm_k(GemmP p, int M, int N, int K) {
    // staging: As 8192 u16 + Bs 8192 u16 = 32KB; epilogue: 128*136*2 = 34816B
    __shared__ __align__(16) u16 smem[128 * LDW];
    u16* As = smem;
    u16* Bs = smem + 8192;

    const int z = blockIdx.z;
    const u16*   __restrict__ B    = p.B[z];
    const float* __restrict__ bias = p.bias[z];

    const int mt  = blockIdx.x * 128;
    const int nt  = blockIdx.y * 128;
    const int tid = threadIdx.x;
    const int l   = tid & 63;
    const int w   = tid >> 6;
    const int wm  = (w >> 1) * 64;
    const int wn  = (w & 1) * 64;
    const int lr  = l & 15;   // MFMA row/col within 16
    const int lk  = l >> 4;   // MFMA k-chunk group (0..3)

    float4v acc[4][4] = {};

    for (int k0 = 0; k0 < K; k0 += 64) {
        // stage A & B tiles (128 rows x 64 k, bf16)
#pragma unroll
        for (int it = 0; it < 4; ++it) {
            int f  = it * 256 + tid;       // 16B chunk id
            int rm = f >> 3, cc = f & 7;
            int gc = cc ^ (rm & 7);
            if (AF32) {
                const float* __restrict__ A32 = (const float*)p.A[z];
                const float* src = A32 + (size_t)(mt + rm) * K + (k0 + cc * 8);
                float4v a = *(const float4v*)src;
                float4v b = *(const float4v*)(src + 4);
                u16x8 r;
                r[0] = f2b(a[0]); r[1] = f2b(a[1]); r[2] = f2b(a[2]); r[3] = f2b(a[3]);
                r[4] = f2b(b[0]); r[5] = f2b(b[1]); r[6] = f2b(b[2]); r[7] = f2b(b[3]);
                // direct-swizzled ds_write: slot (rm, cc^(rm&7)) holds chunk cc
                *(u16x8*)(As + ((size_t)rm * 8 + (cc ^ (rm & 7))) * 8) = r;
            } else {
                const u16* __restrict__ A16 = (const u16*)p.A[z];
                gld16(A16 + (size_t)(mt + rm) * K + (k0 + gc * 8),
                      As + (size_t)f * 8);
            }
            gld16(B + (size_t)(nt + rm) * K + (k0 + gc * 8), Bs + (size_t)f * 8);
        }
        __syncthreads();
#pragma unroll
        for (int ks = 0; ks < 2; ++ks) {
            short8 af[4], bfr[4];
            const int kc = ks * 4 + lk;
#pragma unroll
            for (int i = 0; i < 4; ++i) {
                int ra = wm + i * 16 + lr;
                af[i]  = *(const short8*)(As + ((size_t)ra * 8 + (kc ^ (ra & 7))) * 8);
                int rb = wn + i * 16 + lr;
                bfr[i] = *(const short8*)(Bs + ((size_t)rb * 8 + (kc ^ (rb & 7))) * 8);
            }
#pragma unroll
            for (int i = 0; i < 4; ++i)
#pragma unroll
                for (int j = 0; j < 4; ++j)
                    acc[i][j] = __builtin_amdgcn_mfma_f32_16x16x32_bf16(
                        af[i], bfr[j], acc[i][j], 0, 0, 0);
        }
        __syncthreads();
    }

    // epilogue: C/D layout col=lane&15, row=(lane>>4)*4+reg  [verified m89/m91]
    const int r0 = lk * 4;
#pragma unroll
    for (int j = 0; j < 4; ++j) {
        const int lc = wn + j * 16 + lr;
        const float bv = bias[nt + lc];
#pragma unroll
        for (int i = 0; i < 4; ++i) {
            const int lrow = wm + i * 16 + r0;
#pragma unroll
            for (int r = 0; r < 4; ++r) {
                float v = acc[i][j][r] + bv;
                if (ACT) v = v > 0.f ? v : 0.01f * v;   // jax leaky_relu slope
                smem[(size_t)(lrow + r) * LDW + lc] = f2b(v);
            }
        }
    }
    __syncthreads();
    // 2048 16B chunks, 8 per thread; 16 lanes cover a 256B row segment
#pragma unroll
    for (int pass = 0; pass < 8; ++pass) {
        int id   = pass * 256 + tid;
        int row  = id >> 4, colc = id & 15;
        u16x8 vv = *(const u16x8*)(smem + (size_t)row * LDW + colc * 8);
        *(u16x8*)(p.out[z] + (size_t)(mt + row) * N + nt + colc * 8) = vv;
    }
}

// ---------------------------------------------------------------------------
// LDS-tiled weight transpose+convert: fp32 [K,N] -> bf16 [N,K], 64x64 tiles
// ---------------------------------------------------------------------------
struct TP { const float* src[6]; u16* dst[6]; int K[6]; int N[6]; };

__global__ __launch_bounds__(256) void transpose_k(TP t) {
    __shared__ float tile[64][65];
    const int m = blockIdx.y;
    const int K = t.K[m], N = t.N[m];
    const int tn = N >> 6;
    const int ntiles = (K >> 6) * tn;
    const int bid = blockIdx.x;
    if (bid >= ntiles) return;
    const int k0 = (bid / tn) * 64, n0 = (bid % tn) * 64;
    const int tid = threadIdx.x;
#pragma unroll
    for (int pass = 0; pass < 4; ++pass) {
        int kk = pass * 16 + (tid >> 4);
        int nn = (tid & 15) * 4;
        float4v v = *(const float4v*)(t.src[m] + (size_t)(k0 + kk) * N + n0 + nn);
        tile[kk][nn + 0] = v[0]; tile[kk][nn + 1] = v[1];
        tile[kk][nn + 2] = v[2]; tile[kk][nn + 3] = v[3];
    }
    __syncthreads();
    const int n = tid >> 2, kc = (tid & 3) * 16;
    u16x8 a, b;
#pragma unroll
    for (int j = 0; j < 8; ++j) {
        a[j] = f2b(tile[kc + j][n]);
        b[j] = f2b(tile[kc + 8 + j][n]);
    }
    u16* d = t.dst[m] + (size_t)(n0 + n) * K + k0 + kc;
    *(u16x8*)d = a;
    *(u16x8*)(d + 8) = b;
}

// EW[t][c] = sum_e emb[t][e] * W_edge[e][c]   (64x256, fp32)
__global__ void ew_k(const float* emb, const float* W_edge, float* EW) {
    const int t = blockIdx.x, c = threadIdx.x;
    float s = 0.f;
    for (int e = 0; e < 64; ++e)
        s += emb[t * 64 + e] * W_edge[e * 256 + c];
    EW[t * 256 + c] = s;
}

// bcat = [b_msg | b_self]  (512 fp32)
__global__ void bias_cat_k(const float* bmsg, const float* bself, float* bcat) {
    const int tid = threadIdx.x;
    bcat[tid]       = bmsg[tid];
    bcat[256 + tid] = bself[tid];
}

// ---------------------------------------------------------------------------
// Epilogue: out_i = xself[i] + valid_i*(xmsg[head_i] + EW[type_i]);
//           L2-normalize; accumulate per-batch sum (later /2048).
// alpha == valid exactly (dst=arange -> singleton segments -> softmax = 1).
// xcat[i, 0:256] = xmsg_i, xcat[i, 256:512] = xself_i   (one merged GEMM)
// ---------------------------------------------------------------------------
struct EpiP {
    const u16* xcat[2];
    const int* den[2]; const int* spa[2]; const int* arc[2];
    const int* wty[2]; const int* wma[2];
    const float* EW; float* racc;
};

__global__ __launch_bounds__(256) void epi_k(EpiP p) {
    __shared__ float part[4][256];
    const int bx    = blockIdx.x;
    const int side  = bx >> 9;           // 512 blocks per side
    const int local = bx & 511;
    const int base  = local * 32;        // 32 nodes/block (same batch: 32|2048)
    const int b     = base >> 11;
    const int tid   = threadIdx.x;
    const int w = tid >> 6, l = tid & 63;

    const u16* __restrict__ xcat = p.xcat[side];

    float4v acc = {};
    for (int j = 0; j < 8; ++j) {
        const int i     = base + w * 8 + j;
        const int valid = p.den[side][i] * p.spa[side][i];
        const int srcn  = p.arc[side][i] + (i >> 11) * SEQ;
        const int t     = p.wty[side][i] * p.wma[side][i];
        short4v xs = *(const short4v*)(xcat + (size_t)i * 512 + 256 + l * 4);
        short4v xm = *(const short4v*)(xcat + (size_t)srcn * 512 + l * 4);
        float4v ew = *(const float4v*)(p.EW + (size_t)t * 256 + l * 4);
        const float vm = valid ? 1.f : 0.f;
        float4v v;
        v[0] = b2f((u16)xs[0]) + vm * (b2f((u16)xm[0]) + ew[0]);
        v[1] = b2f((u16)xs[1]) + vm * (b2f((u16)xm[1]) + ew[1]);
        v[2] = b2f((u16)xs[2]) + vm * (b2f((u16)xm[2]) + ew[2]);
        v[3] = b2f((u16)xs[3]) + vm * (b2f((u16)xm[3]) + ew[3]);
        float ss = v[0]*v[0] + v[1]*v[1] + v[2]*v[2] + v[3]*v[3];
        for (int m = 32; m >= 1; m >>= 1) ss += __shfl_xor(ss, m, 64);
        const float rn = 1.f / fmaxf(sqrtf(ss), 1e-12f);
        acc[0] += v[0] * rn; acc[1] += v[1] * rn;
        acc[2] += v[2] * rn; acc[3] += v[3] * rn;
    }
    part[w][l * 4 + 0] = acc[0];
    part[w][l * 4 + 1] = acc[1];
    part[w][l * 4 + 2] = acc[2];
    part[w][l * 4 + 3] = acc[3];
    __syncthreads();
    const float s = part[0][tid] + part[1][tid] + part[2][tid] + part[3][tid];
    atomicAdd(p.racc + ((size_t)side * 8 + b) * 256 + tid, s);
}

// out[side,b,c] = (racc[side,b,:]/2048) @ Wf[:,c] + bf[c]   (fp32 out)
__global__ void fin_k(const float* racc, const float* Wf, const float* bfv,
                      float* out) {
    __shared__ float r[256];
    const int bid = blockIdx.x;   // side*8 + b, 0..15
    const int tid = threadIdx.x;
    r[tid] = racc[bid * 256 + tid] * (1.f / 2048.f);
    __syncthreads();
    float s = bfv[tid];
    for (int k = 0; k < 256; ++k)
        s += r[k] * Wf[k * 256 + tid];
    out[bid * 256 + tid] = s;
}

// ---------------------------------------------------------------------------
extern "C" void kernel_launch(void* const* d_in, const int* in_sizes, int n_in,
                              void* d_out, int out_size, void* d_ws, size_t ws_size,
                              hipStream_t stream) {
    // setup_inputs() dict order; float tensors fp32, index tensors int32
    const float* h[2]   = {(const float*)d_in[0],  (const float*)d_in[1]};
    const int* den[2]   = {(const int*)d_in[4],  (const int*)d_in[11]};
    const int* spa[2]   = {(const int*)d_in[5],  (const int*)d_in[12]};
    const int* arc[2]   = {(const int*)d_in[7],  (const int*)d_in[14]};
    const int* wty[2]   = {(const int*)d_in[9],  (const int*)d_in[16]};
    const int* wma[2]   = {(const int*)d_in[10], (const int*)d_in[17]};
    const float* W1[2]  = {(const float*)d_in[18], (const float*)d_in[22]};
    const float* b1[2]  = {(const float*)d_in[19], (const float*)d_in[23]};
    const float* W2[2]  = {(const float*)d_in[20], (const float*)d_in[24]};
    const float* b2[2]  = {(const float*)d_in[21], (const float*)d_in[25]};
    const float* emb    = (const float*)d_in[26];
    const float* Wmsg   = (const float*)d_in[27];
    const float* bmsg   = (const float*)d_in[28];
    const float* Wedge  = (const float*)d_in[29];
    const float* Wself  = (const float*)d_in[31];
    const float* bself  = (const float*)d_in[32];
    const float* Wf     = (const float*)d_in[33];
    const float* bf_    = (const float*)d_in[34];

    char* ws = (char*)d_ws;
    size_t off = 0;
    auto alloc = [&](size_t bytes) -> void* {
        void* pp = ws + off; off += (bytes + 255) & ~(size_t)255; return pp;
    };
    u16*   x1    = (u16*)  alloc(2ull * NNODE * 512 * 2);   // 32 MB, MLP hidden
    u16*   xx    = (u16*)  alloc(2ull * NNODE * 256 * 2);   // 16 MB, x
    u16*   xcat  = (u16*)  alloc(2ull * NNODE * 512 * 2);   // 32 MB, [msg|self]
    u16*   W1T   = (u16*)  alloc(2ull * 512 * 1024 * 2);
    u16*   W2T   = (u16*)  alloc(2ull * 256 * 512 * 2);
    u16*   WcatT = (u16*)  alloc(512 * 256 * 2);            // [WmsgT ; WselfT]
    float* EW    = (float*)alloc(64 * 256 * 4);
    float* bcat  = (float*)alloc(512 * 4);
    float* racc  = (float*)alloc(2 * 8 * 256 * 4);

    // prep: weights transpose+convert to [N,K] bf16 (LDS-tiled, coalesced)
    TP tp;
    tp.src[0] = W1[0]; tp.dst[0] = W1T;              tp.K[0] = 1024; tp.N[0] = 512;
    tp.src[1] = W1[1]; tp.dst[1] = W1T + 512 * 1024; tp.K[1] = 1024; tp.N[1] = 512;
    tp.src[2] = W2[0]; tp.dst[2] = W2T;              tp.K[2] = 512;  tp.N[2] = 256;
    tp.src[3] = W2[1]; tp.dst[3] = W2T + 256 * 512;  tp.K[3] = 512;  tp.N[3] = 256;
    tp.src[4] = Wmsg;  tp.dst[4] = WcatT;            tp.K[4] = 256;  tp.N[4] = 256;
    tp.src[5] = Wself; tp.dst[5] = WcatT + 256*256;  tp.K[5] = 256;  tp.N[5] = 256;
    hipLaunchKernelGGL(transpose_k, dim3(128, 6), dim3(256), 0, stream, tp);
    hipLaunchKernelGGL(ew_k, dim3(64), dim3(256), 0, stream, emb, Wedge, EW);
    hipLaunchKernelGGL(bias_cat_k, dim3(1), dim3(256), 0, stream, bmsg, bself, bcat);
    hipMemsetAsync(racc, 0, 2 * 8 * 256 * 4, stream);

    // GEMM1 (fused fp32->bf16 A): [16384,1024]@[1024,512]+b1, leaky -> x1
    GemmP g1 = {};
    g1.A[0] = h[0];  g1.A[1] = h[1];
    g1.B[0] = W1T;   g1.B[1] = W1T + 512 * 1024;
    g1.bias[0] = b1[0]; g1.bias[1] = b1[1];
    g1.out[0] = x1;  g1.out[1] = x1 + (size_t)NNODE * 512;
    hipLaunchKernelGGL((gemm_k<1, 1>), dim3(128, 4, 2), dim3(256), 0, stream,
                       g1, NNODE, 512, 1024);

    // GEMM2: [16384,512]@[512,256] + b2 -> x (bf16)
    GemmP g2 = {};
    g2.A[0] = x1;  g2.A[1] = x1 + (size_t)NNODE * 512;
    g2.B[0] = W2T; g2.B[1] = W2T + 256 * 512;
    g2.bias[0] = b2[0]; g2.bias[1] = b2[1];
    g2.out[0] = xx; g2.out[1] = xx + (size_t)NNODE * 256;
    hipLaunchKernelGGL((gemm_k<0, 0>), dim3(128, 2, 2), dim3(256), 0, stream,
                       g2, NNODE, 256, 512);

    // GEMM3 (merged msg|self): [16384,256]@[256,512] + bcat -> xcat
    GemmP g3 = {};
    g3.A[0] = xx;    g3.A[1] = xx + (size_t)NNODE * 256;
    g3.B[0] = WcatT; g3.B[1] = WcatT;
    g3.bias[0] = bcat; g3.bias[1] = bcat;
    g3.out[0] = xcat;  g3.out[1] = xcat + (size_t)NNODE * 512;
    hipLaunchKernelGGL((gemm_k<0, 0>), dim3(128, 4, 2), dim3(256), 0, stream,
                       g3, NNODE, 512, 256);

    // gather + mask + L2-normalize + per-batch mean accumulation
    EpiP ep;
    ep.xcat[0] = xcat; ep.xcat[1] = xcat + (size_t)NNODE * 512;
    for (int s = 0; s < 2; ++s) {
        ep.den[s] = den[s]; ep.spa[s] = spa[s]; ep.arc[s] = arc[s];
        ep.wty[s] = wty[s]; ep.wma[s] = wma[s];
    }
    ep.EW = EW; ep.racc = racc;
    hipLaunchKernelGGL(epi_k, dim3(1024), dim3(256), 0, stream, ep);

    // final projection -> d_out (fp32, src then tgt, 2*8*256)
    hipLaunchKernelGGL(fin_k, dim3(16), dim3(256), 0, stream,
                       racc, Wf, bf_, (float*)d_out);
}

// Round 4
// 314.082 us; speedup vs baseline: 1.1043x; 1.0183x over previous
//
#include <hip/hip_runtime.h>
#include <stdint.h>

// Problem constants
#define SEQ   2048
#define NNODE 16384      // B*S = 8*2048

typedef short  short8  __attribute__((ext_vector_type(8)));   // 8 bf16 (4 VGPR)
typedef float  float4v __attribute__((ext_vector_type(4)));
typedef unsigned short u16;
typedef unsigned short u16x8 __attribute__((ext_vector_type(8)));
typedef short  short4v __attribute__((ext_vector_type(4)));

__device__ __forceinline__ float b2f(u16 u) {
    union { unsigned int i; float f; } x; x.i = ((unsigned int)u) << 16; return x.f;
}
__device__ __forceinline__ u16 f2b(float f) {
    union { float f; unsigned int i; } x; x.f = f;
    unsigned int u = x.i;
    unsigned int r = (u + 0x7fffu + ((u >> 16) & 1u)) >> 16;  // RNE
    return (u16)r;
}

__device__ __forceinline__ void gld16(const void* g, void* l) {
    __builtin_amdgcn_global_load_lds(
        (const __attribute__((address_space(1))) void*)g,
        (__attribute__((address_space(3))) void*)l, 16, 0, 0);
}

// ---------------------------------------------------------------------------
// 128x128 tile bf16 GEMM, double-buffered LDS pipeline (1 barrier / K-iter):
//   iter k: issue async stage of tile k+1 into buf[k+1&1]  (gld16 / reg-prefetch)
//           ds_read frags + 32 MFMA on buf[k&1]
//           (AF32: cvt + ds_write prefetched A regs into buf[k+1&1])
//           __syncthreads  (drains gld16s + LDS writes, releases buf[k&1])
// Rationale: single-buffer structure measured 14k cyc/K-iter vs 1.2k MFMA
// floor -> latency-bound; overlap loads with compute. LDS 64KB -> 2 blk/CU.
// XOR-swizzled LDS chunks: slot (row,c) holds chunk (row, c^(row&7)).
// Epilogue: acc -> LDS (stride 136 u16) -> dwordx4 stores (ampl. 1.0).
// ---------------------------------------------------------------------------
struct GemmP {
    const void*  A[2];
    const u16*   B[2];
    const float* bias[2];
    u16*         out[2];
};

#define LDW 136   // epilogue LDS row stride in u16

template <int ACT, int AF32>
__global__ __launch_bounds__(256, 2) void gemm_k(GemmP p, int M, int N, int K) {
    __shared__ __align__(16) u16 smem[32768];   // 64 KB: 2 bufs x (As 8K + Bs 8K u16)

    const int z = blockIdx.z;
    const u16*   __restrict__ B    = p.B[z];
    const float* __restrict__ bias = p.bias[z];
    const u16*   __restrict__ A16  = (const u16*)p.A[z];
    const float* __restrict__ A32  = (const float*)p.A[z];

    const int mt  = blockIdx.x * 128;
    const int nt  = blockIdx.y * 128;
    const int tid = threadIdx.x;
    const int l   = tid & 63;
    const int w   = tid >> 6;
    const int wm  = (w >> 1) * 64;
    const int wn  = (w & 1) * 64;
    const int lr  = l & 15;   // MFMA row/col within 16
    const int lk  = l >> 4;   // MFMA k-chunk group (0..3)

    float4v acc[4][4] = {};
    float4v pa[8];            // AF32 A-prefetch registers (128 B fp32)

    auto stageB = [&](int k0, u16* Bs) {
#pragma unroll
        for (int it = 0; it < 4; ++it) {
            int f = it * 256 + tid, rm = f >> 3, cc = f & 7, gc = cc ^ (rm & 7);
            gld16(B + (size_t)(nt + rm) * K + (k0 + gc * 8), Bs + (size_t)f * 8);
        }
    };
    auto stageA16 = [&](int k0, u16* As) {
#pragma unroll
        for (int it = 0; it < 4; ++it) {
            int f = it * 256 + tid, rm = f >> 3, cc = f & 7, gc = cc ^ (rm & 7);
            gld16(A16 + (size_t)(mt + rm) * K + (k0 + gc * 8), As + (size_t)f * 8);
        }
    };
    auto prefA32 = [&](int k0) {
#pragma unroll
        for (int it = 0; it < 4; ++it) {
            int f = it * 256 + tid, rm = f >> 3, cc = f & 7;
            const float* s = A32 + (size_t)(mt + rm) * K + k0 + cc * 8;
            pa[2 * it]     = *(const float4v*)s;
            pa[2 * it + 1] = *(const float4v*)(s + 4);
        }
    };
    auto cvtWrite = [&](u16* As) {
#pragma unroll
        for (int it = 0; it < 4; ++it) {
            int f = it * 256 + tid, rm = f >> 3, cc = f & 7;
            float4v a = pa[2 * it], b = pa[2 * it + 1];
            u16x8 r;
            r[0] = f2b(a[0]); r[1] = f2b(a[1]); r[2] = f2b(a[2]); r[3] = f2b(a[3]);
            r[4] = f2b(b[0]); r[5] = f2b(b[1]); r[6] = f2b(b[2]); r[7] = f2b(b[3]);
            *(u16x8*)(As + ((size_t)rm * 8 + (cc ^ (rm & 7))) * 8) = r;
        }
    };

    const int niter = K >> 6;

    // prologue: stage tile 0 into buf 0
    if (AF32) { prefA32(0); cvtWrite(smem); }
    else      { stageA16(0, smem); }
    stageB(0, smem + 8192);
    __syncthreads();

    for (int ki = 0; ki < niter; ++ki) {
        u16* curb = smem + (ki & 1) * 16384;
        u16* nxtb = smem + ((ki & 1) ^ 1) * 16384;
        const bool more = (ki + 1) < niter;
        if (more) {
            if (AF32) prefA32((ki + 1) * 64);
            else      stageA16((ki + 1) * 64, nxtb);
            stageB((ki + 1) * 64, nxtb + 8192);
        }
        const u16* As = curb;
        const u16* Bs = curb + 8192;
#pragma unroll
        for (int ks = 0; ks < 2; ++ks) {
            short8 af[4], bfr[4];
            const int kc = ks * 4 + lk;
#pragma unroll
            for (int i = 0; i < 4; ++i) {
                int ra = wm + i * 16 + lr;
                af[i]  = *(const short8*)(As + ((size_t)ra * 8 + (kc ^ (ra & 7))) * 8);
                int rb = wn + i * 16 + lr;
                bfr[i] = *(const short8*)(Bs + ((size_t)rb * 8 + (kc ^ (rb & 7))) * 8);
            }
#pragma unroll
            for (int i = 0; i < 4; ++i)
#pragma unroll
                for (int j = 0; j < 4; ++j)
                    acc[i][j] = __builtin_amdgcn_mfma_f32_16x16x32_bf16(
                        af[i], bfr[j], acc[i][j], 0, 0, 0);
        }
        if (AF32 && more) cvtWrite(nxtb);   // consume prefetch regs after MFMAs
        __syncthreads();
    }

    // epilogue: C/D layout col=lane&15, row=(lane>>4)*4+reg  [verified m89/m91]
    const int r0 = lk * 4;
#pragma unroll
    for (int j = 0; j < 4; ++j) {
        const int lc = wn + j * 16 + lr;
        const float bv = bias[nt + lc];
#pragma unroll
        for (int i = 0; i < 4; ++i) {
            const int lrow = wm + i * 16 + r0;
#pragma unroll
            for (int r = 0; r < 4; ++r) {
                float v = acc[i][j][r] + bv;
                if (ACT) v = v > 0.f ? v : 0.01f * v;   // jax leaky_relu slope
                smem[(size_t)(lrow + r) * LDW + lc] = f2b(v);
            }
        }
    }
    __syncthreads();
#pragma unroll
    for (int pass = 0; pass < 8; ++pass) {
        int id  = pass * 256 + tid;
        int row = id >> 4, colc = id & 15;
        u16x8 vv = *(const u16x8*)(smem + (size_t)row * LDW + colc * 8);
        *(u16x8*)(p.out[z] + (size_t)(mt + row) * N + nt + colc * 8) = vv;
    }
}

// ---------------------------------------------------------------------------
// LDS-tiled weight transpose+convert: fp32 [K,N] -> bf16 [N,K], 64x64 tiles
// ---------------------------------------------------------------------------
struct TP { const float* src[6]; u16* dst[6]; int K[6]; int N[6]; };

__global__ __launch_bounds__(256) void transpose_k(TP t) {
    __shared__ float tile[64][65];
    const int m = blockIdx.y;
    const int K = t.K[m], N = t.N[m];
    const int tn = N >> 6;
    const int ntiles = (K >> 6) * tn;
    const int bid = blockIdx.x;
    if (bid >= ntiles) return;
    const int k0 = (bid / tn) * 64, n0 = (bid % tn) * 64;
    const int tid = threadIdx.x;
#pragma unroll
    for (int pass = 0; pass < 4; ++pass) {
        int kk = pass * 16 + (tid >> 4);
        int nn = (tid & 15) * 4;
        float4v v = *(const float4v*)(t.src[m] + (size_t)(k0 + kk) * N + n0 + nn);
        tile[kk][nn + 0] = v[0]; tile[kk][nn + 1] = v[1];
        tile[kk][nn + 2] = v[2]; tile[kk][nn + 3] = v[3];
    }
    __syncthreads();
    const int n = tid >> 2, kc = (tid & 3) * 16;
    u16x8 a, b;
#pragma unroll
    for (int j = 0; j < 8; ++j) {
        a[j] = f2b(tile[kc + j][n]);
        b[j] = f2b(tile[kc + 8 + j][n]);
    }
    u16* d = t.dst[m] + (size_t)(n0 + n) * K + k0 + kc;
    *(u16x8*)d = a;
    *(u16x8*)(d + 8) = b;
}

// EW[t][c] = sum_e emb[t][e] * W_edge[e][c]   (64x256, fp32)
__global__ void ew_k(const float* emb, const float* W_edge, float* EW) {
    const int t = blockIdx.x, c = threadIdx.x;
    float s = 0.f;
    for (int e = 0; e < 64; ++e)
        s += emb[t * 64 + e] * W_edge[e * 256 + c];
    EW[t * 256 + c] = s;
}

// bcat = [b_msg | b_self]  (512 fp32)
__global__ void bias_cat_k(const float* bmsg, const float* bself, float* bcat) {
    const int tid = threadIdx.x;
    bcat[tid]       = bmsg[tid];
    bcat[256 + tid] = bself[tid];
}

// ---------------------------------------------------------------------------
// Epilogue: out_i = xself[i] + valid_i*(xmsg[head_i] + EW[type_i]);
//           L2-normalize; accumulate per-batch sum (later /2048).
// alpha == valid exactly (dst=arange -> singleton segments -> softmax = 1).
// xcat[i, 0:256] = xmsg_i, xcat[i, 256:512] = xself_i   (one merged GEMM)
// ---------------------------------------------------------------------------
struct EpiP {
    const u16* xcat[2];
    const int* den[2]; const int* spa[2]; const int* arc[2];
    const int* wty[2]; const int* wma[2];
    const float* EW; float* racc;
};

__global__ __launch_bounds__(256) void epi_k(EpiP p) {
    __shared__ float part[4][256];
    const int bx    = blockIdx.x;
    const int side  = bx >> 9;           // 512 blocks per side
    const int local = bx & 511;
    const int base  = local * 32;        // 32 nodes/block (same batch: 32|2048)
    const int b     = base >> 11;
    const int tid   = threadIdx.x;
    const int w = tid >> 6, l = tid & 63;

    const u16* __restrict__ xcat = p.xcat[side];

    float4v acc = {};
    for (int j = 0; j < 8; ++j) {
        const int i     = base + w * 8 + j;
        const int valid = p.den[side][i] * p.spa[side][i];
        const int srcn  = p.arc[side][i] + (i >> 11) * SEQ;
        const int t     = p.wty[side][i] * p.wma[side][i];
        short4v xs = *(const short4v*)(xcat + (size_t)i * 512 + 256 + l * 4);
        short4v xm = *(const short4v*)(xcat + (size_t)srcn * 512 + l * 4);
        float4v ew = *(const float4v*)(p.EW + (size_t)t * 256 + l * 4);
        const float vm = valid ? 1.f : 0.f;
        float4v v;
        v[0] = b2f((u16)xs[0]) + vm * (b2f((u16)xm[0]) + ew[0]);
        v[1] = b2f((u16)xs[1]) + vm * (b2f((u16)xm[1]) + ew[1]);
        v[2] = b2f((u16)xs[2]) + vm * (b2f((u16)xm[2]) + ew[2]);
        v[3] = b2f((u16)xs[3]) + vm * (b2f((u16)xm[3]) + ew[3]);
        float ss = v[0]*v[0] + v[1]*v[1] + v[2]*v[2] + v[3]*v[3];
        for (int m = 32; m >= 1; m >>= 1) ss += __shfl_xor(ss, m, 64);
        const float rn = 1.f / fmaxf(sqrtf(ss), 1e-12f);
        acc[0] += v[0] * rn; acc[1] += v[1] * rn;
        acc[2] += v[2] * rn; acc[3] += v[3] * rn;
    }
    part[w][l * 4 + 0] = acc[0];
    part[w][l * 4 + 1] = acc[1];
    part[w][l * 4 + 2] = acc[2];
    part[w][l * 4 + 3] = acc[3];
    __syncthreads();
    const float s = part[0][tid] + part[1][tid] + part[2][tid] + part[3][tid];
    atomicAdd(p.racc + ((size_t)side * 8 + b) * 256 + tid, s);
}

// out[side,b,c] = (racc[side,b,:]/2048) @ Wf[:,c] + bf[c]   (fp32 out)
__global__ void fin_k(const float* racc, const float* Wf, const float* bfv,
                      float* out) {
    __shared__ float r[256];
    const int bid = blockIdx.x;   // side*8 + b, 0..15
    const int tid = threadIdx.x;
    r[tid] = racc[bid * 256 + tid] * (1.f / 2048.f);
    __syncthreads();
    float s = bfv[tid];
    for (int k = 0; k < 256; ++k)
        s += r[k] * Wf[k * 256 + tid];
    out[bid * 256 + tid] = s;
}

// ---------------------------------------------------------------------------
extern "C" void kernel_launch(void* const* d_in, const int* in_sizes, int n_in,
                              void* d_out, int out_size, void* d_ws, size_t ws_size,
                              hipStream_t stream) {
    // setup_inputs() dict order; float tensors fp32, index tensors int32
    const float* h[2]   = {(const float*)d_in[0],  (const float*)d_in[1]};
    const int* den[2]   = {(const int*)d_in[4],  (const int*)d_in[11]};
    const int* spa[2]   = {(const int*)d_in[5],  (const int*)d_in[12]};
    const int* arc[2]   = {(const int*)d_in[7],  (const int*)d_in[14]};
    const int* wty[2]   = {(const int*)d_in[9],  (const int*)d_in[16]};
    const int* wma[2]   = {(const int*)d_in[10], (const int*)d_in[17]};
    const float* W1[2]  = {(const float*)d_in[18], (const float*)d_in[22]};
    const float* b1[2]  = {(const float*)d_in[19], (const float*)d_in[23]};
    const float* W2[2]  = {(const float*)d_in[20], (const float*)d_in[24]};
    const float* b2[2]  = {(const float*)d_in[21], (const float*)d_in[25]};
    const float* emb    = (const float*)d_in[26];
    const float* Wmsg   = (const float*)d_in[27];
    const float* bmsg   = (const float*)d_in[28];
    const float* Wedge  = (const float*)d_in[29];
    const float* Wself  = (const float*)d_in[31];
    const float* bself  = (const float*)d_in[32];
    const float* Wf     = (const float*)d_in[33];
    const float* bf_    = (const float*)d_in[34];

    char* ws = (char*)d_ws;
    size_t off = 0;
    auto alloc = [&](size_t bytes) -> void* {
        void* pp = ws + off; off += (bytes + 255) & ~(size_t)255; return pp;
    };
    u16*   x1    = (u16*)  alloc(2ull * NNODE * 512 * 2);   // 32 MB, MLP hidden
    u16*   xx    = (u16*)  alloc(2ull * NNODE * 256 * 2);   // 16 MB, x
    u16*   xcat  = (u16*)  alloc(2ull * NNODE * 512 * 2);   // 32 MB, [msg|self]
    u16*   W1T   = (u16*)  alloc(2ull * 512 * 1024 * 2);
    u16*   W2T   = (u16*)  alloc(2ull * 256 * 512 * 2);
    u16*   WcatT = (u16*)  alloc(512 * 256 * 2);            // [WmsgT ; WselfT]
    float* EW    = (float*)alloc(64 * 256 * 4);
    float* bcat  = (float*)alloc(512 * 4);
    float* racc  = (float*)alloc(2 * 8 * 256 * 4);

    // prep: weights transpose+convert to [N,K] bf16 (LDS-tiled, coalesced)
    TP tp;
    tp.src[0] = W1[0]; tp.dst[0] = W1T;              tp.K[0] = 1024; tp.N[0] = 512;
    tp.src[1] = W1[1]; tp.dst[1] = W1T + 512 * 1024; tp.K[1] = 1024; tp.N[1] = 512;
    tp.src[2] = W2[0]; tp.dst[2] = W2T;              tp.K[2] = 512;  tp.N[2] = 256;
    tp.src[3] = W2[1]; tp.dst[3] = W2T + 256 * 512;  tp.K[3] = 512;  tp.N[3] = 256;
    tp.src[4] = Wmsg;  tp.dst[4] = WcatT;            tp.K[4] = 256;  tp.N[4] = 256;
    tp.src[5] = Wself; tp.dst[5] = WcatT + 256*256;  tp.K[5] = 256;  tp.N[5] = 256;
    hipLaunchKernelGGL(transpose_k, dim3(128, 6), dim3(256), 0, stream, tp);
    hipLaunchKernelGGL(ew_k, dim3(64), dim3(256), 0, stream, emb, Wedge, EW);
    hipLaunchKernelGGL(bias_cat_k, dim3(1), dim3(256), 0, stream, bmsg, bself, bcat);
    hipMemsetAsync(racc, 0, 2 * 8 * 256 * 4, stream);

    // GEMM1 (fused fp32->bf16 A, reg-prefetch): [16384,1024]@[1024,512]+b1, leaky
    GemmP g1 = {};
    g1.A[0] = h[0];  g1.A[1] = h[1];
    g1.B[0] = W1T;   g1.B[1] = W1T + 512 * 1024;
    g1.bias[0] = b1[0]; g1.bias[1] = b1[1];
    g1.out[0] = x1;  g1.out[1] = x1 + (size_t)NNODE * 512;
    hipLaunchKernelGGL((gemm_k<1, 1>), dim3(128, 4, 2), dim3(256), 0, stream,
                       g1, NNODE, 512, 1024);

    // GEMM2: [16384,512]@[512,256] + b2 -> x (bf16)
    GemmP g2 = {};
    g2.A[0] = x1;  g2.A[1] = x1 + (size_t)NNODE * 512;
    g2.B[0] = W2T; g2.B[1] = W2T + 256 * 512;
    g2.bias[0] = b2[0]; g2.bias[1] = b2[1];
    g2.out[0] = xx; g2.out[1] = xx + (size_t)NNODE * 256;
    hipLaunchKernelGGL((gemm_k<0, 0>), dim3(128, 2, 2), dim3(256), 0, stream,
                       g2, NNODE, 256, 512);

    // GEMM3 (merged msg|self): [16384,256]@[256,512] + bcat -> xcat
    GemmP g3 = {};
    g3.A[0] = xx;    g3.A[1] = xx + (size_t)NNODE * 256;
    g3.B[0] = WcatT; g3.B[1] = WcatT;
    g3.bias[0] = bcat; g3.bias[1] = bcat;
    g3.out[0] = xcat;  g3.out[1] = xcat + (size_t)NNODE * 512;
    hipLaunchKernelGGL((gemm_k<0, 0>), dim3(128, 4, 2), dim3(256), 0, stream,
                       g3, NNODE, 512, 256);

    // gather + mask + L2-normalize + per-batch mean accumulation
    EpiP ep;
    ep.xcat[0] = xcat; ep.xcat[1] = xcat + (size_t)NNODE * 512;
    for (int s = 0; s < 2; ++s) {
        ep.den[s] = den[s]; ep.spa[s] = spa[s]; ep.arc[s] = arc[s];
        ep.wty[s] = wty[s]; ep.wma[s] = wma[s];
    }
    ep.EW = EW; ep.racc = racc;
    hipLaunchKernelGGL(epi_k, dim3(1024), dim3(256), 0, stream, ep);

    // final projection -> d_out (fp32, src then tgt, 2*8*256)
    hipLaunchKernelGGL(fin_k, dim3(16), dim3(256), 0, stream,
                       racc, Wf, bf_, (float*)d_out);
}